// Round 21
// baseline (149.351 us; speedup 1.0000x reference)
//
#include <hip/hip_runtime.h>
#include <math.h>

// Problem constants
#define BATCH 8192
#define NFEAT 256
#define NH1   100     // fc1 width (K of fc2)
#define NH2   50      // fc2 width (N of fc2)
#define KP    128     // K padded: 4 MFMA k-steps of 32
#define FPB   8       // features per block (inner loop)
#define RPB   256     // batch rows per block (32 per wave, 8 waves)

typedef __attribute__((ext_vector_type(8))) _Float16 half8;   // MFMA A/B frag
typedef __attribute__((ext_vector_type(2))) _Float16 h2v;     // packed fp16 pair
typedef __attribute__((ext_vector_type(4))) float    float4v; // MFMA acc

// ---- workspace layout (fp32 units from ws start) ----
// w2h : NFEAT*8192 f16 = 4 MB (fragment-ordered, zero-padded)
// w1h/b1h : NFEAT*KP f16 (zero-padded)
#define OFF_W1H  (NFEAT * 8192 / 2)
#define OFF_B1H  (OFF_W1H + NFEAT * KP / 2)

// ---- prep v2 (R16): grid = (4 kk-quarters, NFEAT). Coalesced W2 slice ->
// LDS (stride 40, 2-way aliasing = free) -> coalesced fragment stores.
__global__ __launch_bounds__(256) void prep(
    const float* __restrict__ W1, const float* __restrict__ b1,
    const float* __restrict__ W2, float* __restrict__ ws,
    float* __restrict__ out)
{
    __shared__ float l2[NH2 * 40];       // 8 KB
    const int q = blockIdx.x;            // kk quarter 0..3
    const int f = blockIdx.y;
    const int t = threadIdx.x;

    if (q == 0) {
        _Float16* w1h = (_Float16*)(ws + OFF_W1H) + f * KP;
        _Float16* b1h = (_Float16*)(ws + OFF_B1H) + f * KP;
        if (t < KP) {
            w1h[t] = (_Float16)((t < NH1) ? W1[f * NH1 + t] : 0.f);
            b1h[t] = (_Float16)((t < NH1) ? b1[f * NH1 + t] : 0.f);
        }
        if (t < 32) out[f * 32 + t] = 0.f;
    }

    const float* __restrict__ w2g = W2 + (size_t)f * NH2 * NH1;
#pragma unroll
    for (int i = 0; i < 7; ++i) {
        const int idx = i * 256 + t;
        if (idx < NH2 * 32) {
            const int o = idx >> 5, hh = idx & 31, h = q * 32 + hh;
            l2[o * 40 + hh] = (h < NH1) ? w2g[o * NH1 + h] : 0.f;
        }
    }
    __syncthreads();

    _Float16* w2h = (_Float16*)ws + (size_t)f * 8192 + q * 2048;
#pragma unroll
    for (int i = 0; i < 8; ++i) {
        const int el   = i * 256 + t;          // 0..2047
        const int j    = el & 7;
        const int lane = (el >> 3) & 63;
        const int nt   = (el >> 9) & 3;
        const int o    = nt * 16 + (lane & 15);
        const int hl   = (lane >> 4) * 8 + j;
        w2h[el] = (_Float16)((o < NH2) ? l2[o * 40 + hl] : 0.f);
    }
}

// async 16KB stage for 512-thread block: 2 x (512 lanes x 16B) DMA.
__device__ __forceinline__ void stage_async(
    const _Float16* __restrict__ src, _Float16* dst, int t)
{
#pragma unroll
    for (int i = 0; i < 2; ++i) {
        const _Float16* g = src + (i * 512 + t) * 8;
        _Float16* l       = dst + (i * 512 + t) * 8;
        __builtin_amdgcn_global_load_lds(
            (const __attribute__((address_space(1))) unsigned*)g,
            (__attribute__((address_space(3))) unsigned*)l, 16, 0, 0);
    }
}

// ---- main: R20 body with the x-tile stored fp16 TRANSPOSED (xshh[fi][row],
// 4 KB instead of 8): LDS total drops 44->40 KB => 4 blocks/CU (was 3,
// LDS-capped at Occ 34%), and the in-loop x reads become row-consecutive
// halfwords (kills R20's 786K 4-way conflicts from the stride-8 layout).
// x rounded RNE once at staging (replaces per-f RTZ splat). Everything
// else identical to R20.
__global__ __launch_bounds__(512, 8) void nam_mfma(
    const float* __restrict__ x,
    const float* __restrict__ ws,
    const float* __restrict__ b2,
    const float* __restrict__ W3,
    float* __restrict__ out)
{
    __shared__ _Float16 lds[2][8192];      // 32 KB: B-fragment double buffer
    __shared__ _Float16 xshh[FPB * RPB];   // 4 KB: x[fi][row] fp16
    __shared__ _Float16 wsh[FPB * KP];     // 2 KB: W1 slices
    __shared__ _Float16 csh[FPB * KP];     // 2 KB: b1 slices

    const int t   = threadIdx.x;
    const int wv  = t >> 6;                // wave 0..7
    const int l64 = t & 63;
    const int ln  = t & 15;
    const int qd  = (t >> 4) & 3;
    const int rowbase = blockIdx.x * RPB + wv * 32;
    const int f0      = blockIdx.y * FPB;

    const _Float16* w2h = (const _Float16*)ws;
    const _Float16* w1h = (const _Float16*)(ws + OFF_W1H);
    const _Float16* b1h = (const _Float16*)(ws + OFF_B1H);

    int osrc[4];
#pragma unroll
    for (int nt = 0; nt < 4; ++nt) {
        const int o = nt * 16 + ln;
        osrc[nt] = (o < NH2) ? o : 0;      // clamped; killed by wo=0
    }

    // ---- one-time staging: B f0 (async) + x tile (fp16 transposed) + w1/b1
    stage_async(w2h + (size_t)f0 * 8192, lds[0], t);
    {
        const int r = t >> 1, half = t & 1;           // 512 thr: 256 rows x 2
        const float4 v = *(const float4*)(
            x + (size_t)(blockIdx.x * RPB + r) * NFEAT + f0 + half * 4);
        xshh[(half * 4 + 0) * RPB + r] = (_Float16)v.x;
        xshh[(half * 4 + 1) * RPB + r] = (_Float16)v.y;
        xshh[(half * 4 + 2) * RPB + r] = (_Float16)v.z;
        xshh[(half * 4 + 3) * RPB + r] = (_Float16)v.w;
    }
    if (t < 128)
        ((int4*)wsh)[t] = ((const int4*)(w1h + (size_t)f0 * KP))[t];
    else if (t < 256)
        ((int4*)csh)[t - 128] = ((const int4*)(b1h + (size_t)f0 * KP))[t - 128];
    __syncthreads();

    float rp[2][4] = {{0.f}, {0.f}};       // contrib, summed over f

#pragma unroll 1
    for (int fi = 0; fi < FPB; ++fi) {
        const int f = f0 + fi;
        const _Float16* B = lds[fi & 1];

        // DMA f+1 into the other buffer; lands by this iter's end barrier
        if (fi + 1 < FPB)
            stage_async(w2h + (size_t)(f + 1) * 8192, lds[(fi + 1) & 1], t);

        // x from LDS: row-consecutive halfwords, broadcast across quads
        h2v xh[2];
#pragma unroll
        for (int mt = 0; mt < 2; ++mt) {
            const _Float16 xs = xshh[fi * RPB + wv * 32 + mt * 16 + ln];
            xh[mt] = (h2v){xs, xs};
        }

        float4v acc[2][4];
#pragma unroll
        for (int mt = 0; mt < 2; ++mt)
#pragma unroll
            for (int nt = 0; nt < 4; ++nt) acc[mt][nt] = (float4v){0.f, 0.f, 0.f, 0.f};

        const h2v z2 = (h2v){(_Float16)0.f, (_Float16)0.f};

#pragma unroll
        for (int kk = 0; kk < 4; ++kk) {
            half8 bf[4];
#pragma unroll
            for (int nt = 0; nt < 4; ++nt)
                bf[nt] = *(const half8*)(B + (kk * 4 + nt) * 512 + l64 * 8);

            // w1/b1 fragment: one ds_read_b128 each (contiguous 8 f16)
            const half8 wv8 = *(const half8*)(wsh + fi * KP + kk * 32 + qd * 8);
            const half8 cv8 = *(const half8*)(csh + fi * KP + kk * 32 + qd * 8);
            const h2v* wpp = (const h2v*)&wv8;
            const h2v* cpp = (const h2v*)&cv8;

#pragma unroll
            for (int mt = 0; mt < 2; ++mt) {
                half8 af;
                h2v* ap = (h2v*)&af;
                ap[0] = __builtin_elementwise_max(wpp[0] * xh[mt] + cpp[0], z2);
                ap[1] = __builtin_elementwise_max(wpp[1] * xh[mt] + cpp[1], z2);
                ap[2] = __builtin_elementwise_max(wpp[2] * xh[mt] + cpp[2], z2);
                ap[3] = __builtin_elementwise_max(wpp[3] * xh[mt] + cpp[3], z2);
#pragma unroll
                for (int nt = 0; nt < 4; ++nt)
                    acc[mt][nt] = __builtin_amdgcn_mfma_f32_16x16x32_f16(
                        af, bf[nt], acc[mt][nt], 0, 0, 0);
            }
        }

        // epilogue for this f: h2 = relu(acc + b2); rp += h2 * w3
        const float* __restrict__ b2g = b2 + f * NH2;
        const float* __restrict__ w3g = W3 + f * NH2;
#pragma unroll
        for (int nt = 0; nt < 4; ++nt) {
            const int o = nt * 16 + ln;
            const float bo = b2g[osrc[nt]];
            const float wo = (o < NH2) ? w3g[osrc[nt]] : 0.f;
#pragma unroll
            for (int mt = 0; mt < 2; ++mt)
#pragma unroll
                for (int r = 0; r < 4; ++r)
                    rp[mt][r] = fmaf(fmaxf(acc[mt][nt][r] + bo, 0.f), wo, rp[mt][r]);
        }

        __syncthreads();   // drains DMA (f+1 ready) + releases buffer fi&1
    }

    // ---- shuffle-reduce rp over the 16 columns, one atomic per row ----
#pragma unroll
    for (int mt = 0; mt < 2; ++mt)
#pragma unroll
        for (int r = 0; r < 4; ++r) {
            float v = rp[mt][r];
            v += __shfl_xor(v, 1);
            v += __shfl_xor(v, 2);
            v += __shfl_xor(v, 4);
            v += __shfl_xor(v, 8);
            if (ln == 0)
                atomicAdd(out + rowbase + mt * 16 + qd * 4 + r, v);
        }
}

__global__ __launch_bounds__(256) void nam_finish(
    float* __restrict__ out, const float* __restrict__ bias)
{
    const int b = blockIdx.x * blockDim.x + threadIdx.x;
    out[b] = 1.0f / (1.0f + expf(-(out[b] + bias[0])));
}

extern "C" void kernel_launch(void* const* d_in, const int* in_sizes, int n_in,
                              void* d_out, int out_size, void* d_ws, size_t ws_size,
                              hipStream_t stream) {
    const float* x    = (const float*)d_in[0];
    const float* W1   = (const float*)d_in[1];
    const float* b1   = (const float*)d_in[2];
    const float* W2   = (const float*)d_in[3];
    const float* b2   = (const float*)d_in[4];
    const float* W3   = (const float*)d_in[5];
    const float* bias = (const float*)d_in[6];
    float* out = (float*)d_out;
    float* ws  = (float*)d_ws;   // ~4.3 MB used

    prep<<<dim3(4, NFEAT), 256, 0, stream>>>(W1, b1, W2, ws, out);

    nam_mfma<<<dim3(BATCH / RPB, NFEAT / FPB), 512, 0, stream>>>(
        x, ws, b2, W3, out);

    nam_finish<<<BATCH / 256, 256, 0, stream>>>(out, bias);
}

// Round 22
// 114.176 us; speedup vs baseline: 1.3081x; 1.3081x over previous
//
#include <hip/hip_runtime.h>
#include <math.h>

// Problem constants
#define BATCH 8192
#define NFEAT 256
#define NH1   100     // fc1 width (K of fc2)
#define NH2   50      // fc2 width (N of fc2)
#define KP    128     // K padded: 4 MFMA k-steps of 32
#define FPB   8       // features per block (inner loop)
#define RPB   256     // batch rows per block (32 per wave, 8 waves)

typedef __attribute__((ext_vector_type(8))) _Float16 half8;   // MFMA A/B frag
typedef __attribute__((ext_vector_type(2))) _Float16 h2v;     // packed fp16 pair
typedef __attribute__((ext_vector_type(4))) float    float4v; // MFMA acc

// ---- workspace layout (fp32 units from ws start) ----
// w2h : NFEAT*8192 f16 = 4 MB (fragment-ordered, zero-padded)
// w1h/b1h : NFEAT*KP f16 (zero-padded)
#define OFF_W1H  (NFEAT * 8192 / 2)
#define OFF_B1H  (OFF_W1H + NFEAT * KP / 2)

// ---- prep v2 (R16): grid = (4 kk-quarters, NFEAT). Coalesced W2 slice ->
// LDS (stride 40, 2-way aliasing = free) -> coalesced fragment stores.
__global__ __launch_bounds__(256) void prep(
    const float* __restrict__ W1, const float* __restrict__ b1,
    const float* __restrict__ W2, float* __restrict__ ws,
    float* __restrict__ out)
{
    __shared__ float l2[NH2 * 40];       // 8 KB
    const int q = blockIdx.x;            // kk quarter 0..3
    const int f = blockIdx.y;
    const int t = threadIdx.x;

    if (q == 0) {
        _Float16* w1h = (_Float16*)(ws + OFF_W1H) + f * KP;
        _Float16* b1h = (_Float16*)(ws + OFF_B1H) + f * KP;
        if (t < KP) {
            w1h[t] = (_Float16)((t < NH1) ? W1[f * NH1 + t] : 0.f);
            b1h[t] = (_Float16)((t < NH1) ? b1[f * NH1 + t] : 0.f);
        }
        if (t < 32) out[f * 32 + t] = 0.f;
    }

    const float* __restrict__ w2g = W2 + (size_t)f * NH2 * NH1;
#pragma unroll
    for (int i = 0; i < 7; ++i) {
        const int idx = i * 256 + t;
        if (idx < NH2 * 32) {
            const int o = idx >> 5, hh = idx & 31, h = q * 32 + hh;
            l2[o * 40 + hh] = (h < NH1) ? w2g[o * NH1 + h] : 0.f;
        }
    }
    __syncthreads();

    _Float16* w2h = (_Float16*)ws + (size_t)f * 8192 + q * 2048;
#pragma unroll
    for (int i = 0; i < 8; ++i) {
        const int el   = i * 256 + t;          // 0..2047
        const int j    = el & 7;
        const int lane = (el >> 3) & 63;
        const int nt   = (el >> 9) & 3;
        const int o    = nt * 16 + (lane & 15);
        const int hl   = (lane >> 4) * 8 + j;
        w2h[el] = (_Float16)((o < NH2) ? l2[o * 40 + hl] : 0.f);
    }
}

// async 16KB stage for 512-thread block: 2 x (512 lanes x 16B) DMA.
__device__ __forceinline__ void stage_async(
    const _Float16* __restrict__ src, _Float16* dst, int t)
{
#pragma unroll
    for (int i = 0; i < 2; ++i) {
        const _Float16* g = src + (i * 512 + t) * 8;
        _Float16* l       = dst + (i * 512 + t) * 8;
        __builtin_amdgcn_global_load_lds(
            (const __attribute__((address_space(1))) unsigned*)g,
            (__attribute__((address_space(3))) unsigned*)l, 16, 0, 0);
    }
}

// ---- main: R20 body (45.9us best) + fp16 TRANSPOSED x-tile (xshh[fi][row],
// 4 KB vs 8): kills R20's 786K 4-way conflicts (in-loop x reads become
// consecutive-halfword broadcasts) and trims LDS 44->40 KB. Declaration
// stays (512,4): budget 128 regs/wave >= ~80 live -> NO spill (R16's
// (256,4)@144 and R21's (512,8)@80-vs-64 both spilled; never declare more
// min-waves than the live register set affords).
__global__ __launch_bounds__(512, 4) void nam_mfma(
    const float* __restrict__ x,
    const float* __restrict__ ws,
    const float* __restrict__ b2,
    const float* __restrict__ W3,
    float* __restrict__ out)
{
    __shared__ _Float16 lds[2][8192];      // 32 KB: B-fragment double buffer
    __shared__ _Float16 xshh[FPB * RPB];   // 4 KB: x[fi][row] fp16
    __shared__ _Float16 wsh[FPB * KP];     // 2 KB: W1 slices
    __shared__ _Float16 csh[FPB * KP];     // 2 KB: b1 slices

    const int t   = threadIdx.x;
    const int wv  = t >> 6;                // wave 0..7
    const int l64 = t & 63;
    const int ln  = t & 15;
    const int qd  = (t >> 4) & 3;
    const int rowbase = blockIdx.x * RPB + wv * 32;
    const int f0      = blockIdx.y * FPB;

    const _Float16* w2h = (const _Float16*)ws;
    const _Float16* w1h = (const _Float16*)(ws + OFF_W1H);
    const _Float16* b1h = (const _Float16*)(ws + OFF_B1H);

    int osrc[4];
#pragma unroll
    for (int nt = 0; nt < 4; ++nt) {
        const int o = nt * 16 + ln;
        osrc[nt] = (o < NH2) ? o : 0;      // clamped; killed by wo=0
    }

    // ---- one-time staging: B f0 (async) + x tile (fp16 transposed) + w1/b1
    stage_async(w2h + (size_t)f0 * 8192, lds[0], t);
    {
        const int r = t >> 1, half = t & 1;           // 512 thr: 256 rows x 2
        const float4 v = *(const float4*)(
            x + (size_t)(blockIdx.x * RPB + r) * NFEAT + f0 + half * 4);
        xshh[(half * 4 + 0) * RPB + r] = (_Float16)v.x;
        xshh[(half * 4 + 1) * RPB + r] = (_Float16)v.y;
        xshh[(half * 4 + 2) * RPB + r] = (_Float16)v.z;
        xshh[(half * 4 + 3) * RPB + r] = (_Float16)v.w;
    }
    if (t < 128)
        ((int4*)wsh)[t] = ((const int4*)(w1h + (size_t)f0 * KP))[t];
    else if (t < 256)
        ((int4*)csh)[t - 128] = ((const int4*)(b1h + (size_t)f0 * KP))[t - 128];
    __syncthreads();

    float rp[2][4] = {{0.f}, {0.f}};       // contrib, summed over f

#pragma unroll 1
    for (int fi = 0; fi < FPB; ++fi) {
        const int f = f0 + fi;
        const _Float16* B = lds[fi & 1];

        // DMA f+1 into the other buffer; lands by this iter's end barrier
        if (fi + 1 < FPB)
            stage_async(w2h + (size_t)(f + 1) * 8192, lds[(fi + 1) & 1], t);

        // x from LDS: consecutive halfwords, broadcast across quads
        h2v xh[2];
#pragma unroll
        for (int mt = 0; mt < 2; ++mt) {
            const _Float16 xs = xshh[fi * RPB + wv * 32 + mt * 16 + ln];
            xh[mt] = (h2v){xs, xs};
        }

        float4v acc[2][4];
#pragma unroll
        for (int mt = 0; mt < 2; ++mt)
#pragma unroll
            for (int nt = 0; nt < 4; ++nt) acc[mt][nt] = (float4v){0.f, 0.f, 0.f, 0.f};

        const h2v z2 = (h2v){(_Float16)0.f, (_Float16)0.f};

#pragma unroll
        for (int kk = 0; kk < 4; ++kk) {
            half8 bf[4];
#pragma unroll
            for (int nt = 0; nt < 4; ++nt)
                bf[nt] = *(const half8*)(B + (kk * 4 + nt) * 512 + l64 * 8);

            // w1/b1 fragment: one ds_read_b128 each (contiguous 8 f16)
            const half8 wv8 = *(const half8*)(wsh + fi * KP + kk * 32 + qd * 8);
            const half8 cv8 = *(const half8*)(csh + fi * KP + kk * 32 + qd * 8);
            const h2v* wpp = (const h2v*)&wv8;
            const h2v* cpp = (const h2v*)&cv8;

#pragma unroll
            for (int mt = 0; mt < 2; ++mt) {
                half8 af;
                h2v* ap = (h2v*)&af;
                ap[0] = __builtin_elementwise_max(wpp[0] * xh[mt] + cpp[0], z2);
                ap[1] = __builtin_elementwise_max(wpp[1] * xh[mt] + cpp[1], z2);
                ap[2] = __builtin_elementwise_max(wpp[2] * xh[mt] + cpp[2], z2);
                ap[3] = __builtin_elementwise_max(wpp[3] * xh[mt] + cpp[3], z2);
#pragma unroll
                for (int nt = 0; nt < 4; ++nt)
                    acc[mt][nt] = __builtin_amdgcn_mfma_f32_16x16x32_f16(
                        af, bf[nt], acc[mt][nt], 0, 0, 0);
            }
        }

        // epilogue for this f: h2 = relu(acc + b2); rp += h2 * w3
        const float* __restrict__ b2g = b2 + f * NH2;
        const float* __restrict__ w3g = W3 + f * NH2;
#pragma unroll
        for (int nt = 0; nt < 4; ++nt) {
            const int o = nt * 16 + ln;
            const float bo = b2g[osrc[nt]];
            const float wo = (o < NH2) ? w3g[osrc[nt]] : 0.f;
#pragma unroll
            for (int mt = 0; mt < 2; ++mt)
#pragma unroll
                for (int r = 0; r < 4; ++r)
                    rp[mt][r] = fmaf(fmaxf(acc[mt][nt][r] + bo, 0.f), wo, rp[mt][r]);
        }

        __syncthreads();   // drains DMA (f+1 ready) + releases buffer fi&1
    }

    // ---- shuffle-reduce rp over the 16 columns, one atomic per row ----
#pragma unroll
    for (int mt = 0; mt < 2; ++mt)
#pragma unroll
        for (int r = 0; r < 4; ++r) {
            float v = rp[mt][r];
            v += __shfl_xor(v, 1);
            v += __shfl_xor(v, 2);
            v += __shfl_xor(v, 4);
            v += __shfl_xor(v, 8);
            if (ln == 0)
                atomicAdd(out + rowbase + mt * 16 + qd * 4 + r, v);
        }
}

__global__ __launch_bounds__(256) void nam_finish(
    float* __restrict__ out, const float* __restrict__ bias)
{
    const int b = blockIdx.x * blockDim.x + threadIdx.x;
    out[b] = 1.0f / (1.0f + expf(-(out[b] + bias[0])));
}

extern "C" void kernel_launch(void* const* d_in, const int* in_sizes, int n_in,
                              void* d_out, int out_size, void* d_ws, size_t ws_size,
                              hipStream_t stream) {
    const float* x    = (const float*)d_in[0];
    const float* W1   = (const float*)d_in[1];
    const float* b1   = (const float*)d_in[2];
    const float* W2   = (const float*)d_in[3];
    const float* b2   = (const float*)d_in[4];
    const float* W3   = (const float*)d_in[5];
    const float* bias = (const float*)d_in[6];
    float* out = (float*)d_out;
    float* ws  = (float*)d_ws;   // ~4.3 MB used

    prep<<<dim3(4, NFEAT), 256, 0, stream>>>(W1, b1, W2, ws, out);

    nam_mfma<<<dim3(BATCH / RPB, NFEAT / FPB), 512, 0, stream>>>(
        x, ws, b2, W3, out);

    nam_finish<<<BATCH / 256, 256, 0, stream>>>(out, bias);
}